// Round 1
// baseline (696.262 us; speedup 1.0000x reference)
//
#include <hip/hip_runtime.h>

// EchoStateNetwork: h_t = tanh(x_t @ W_in + h_{t-1} @ W_res)
//   x:     [512, 1024, 6]  fp32
//   W_in:  [6, 128]        fp32
//   W_res: [128, 128]      fp32
//   out:   [512, 1024, 128] fp32
//
// Design (round 1, fp32 VALU baseline):
//  - 512 blocks (one per batch row), 256 threads (4 waves) each -> 2 blocks/CU,
//    all 256 CUs busy (tanh + FMA work must be spread chip-wide).
//  - W_res slice register-resident: thread (r, ks) holds W_res[64*ks + j][r],
//    j=0..63 (64 VGPRs). Avoids the ~131 kB/CU/step LDS streaming of W.
//  - h double-buffered in LDS; read as uniform float4 broadcasts.
//  - K-split (ks = lane bit 5) reduced in-wave via shfl_xor(32); one
//    __syncthreads per step.
//  - x row staged in LDS once (24 KB).

#define SEQ 1024
#define CIN 6
#define RES 128

__device__ __forceinline__ float fast_tanh(float x) {
    // tanh(x) = 1 - 2/(exp2(2*log2e*x) + 1); exact at +-inf, ~1e-7 abs err.
    float e = __builtin_exp2f(x * 2.88539008177793f);
    return 1.0f - 2.0f * __builtin_amdgcn_rcpf(e + 1.0f);
}

__global__ __launch_bounds__(256, 2) void esn_fwd(
    const float* __restrict__ x,      // [B, S, 6]
    const float* __restrict__ W_in,   // [6, 128]
    const float* __restrict__ W_res,  // [128, 128]
    float* __restrict__ out)          // [B, S, 128]
{
    __shared__ float x_lds[SEQ * CIN];   // 24 KB
    __shared__ float h_lds[2][RES];      // ping-pong state

    const int t    = threadIdx.x;
    const int row  = blockIdx.x;
    const int lane = t & 63;
    const int w    = t >> 6;
    const int r    = (w << 5) | (lane & 31);  // output index 0..127
    const int ks   = lane >> 5;               // K-split half: 0 or 1

    // Stage this row's x into LDS (coalesced, 24 floats/thread).
    const float* xrow = x + (size_t)row * SEQ * CIN;
    for (int i = t; i < SEQ * CIN; i += 256) x_lds[i] = xrow[i];

    // W_in column r -> 6 registers.
    float win[CIN];
#pragma unroll
    for (int c = 0; c < CIN; ++c) win[c] = W_in[c * RES + r];

    // W_res[64*ks + j][r] -> 64 registers (static indexing only).
    float wreg[64];
#pragma unroll
    for (int j = 0; j < 64; ++j) wreg[j] = W_res[(64 * ks + j) * RES + r];

    if (lane < 32) h_lds[0][r] = 0.0f;
    __syncthreads();

    float* outp = out + (size_t)row * SEQ * RES + r;

    for (int s = 0; s < SEQ; ++s) {
        const int cur = s & 1;

        // bias = x_t @ W_in (only ks==0 half contributes; folded by the reduce)
        float acc;
        {
            const float2* xp = (const float2*)&x_lds[s * CIN];  // 8B-aligned
            float2 a = xp[0], b = xp[1], c2 = xp[2];
            float bias = a.x * win[0] + a.y * win[1] + b.x * win[2]
                       + b.y * win[3] + c2.x * win[4] + c2.y * win[5];
            acc = ks ? 0.0f : bias;
        }

        // 64-length partial dot: h[64*ks + j] * W_res[64*ks + j][r]
        const float4* hp = (const float4*)&h_lds[cur][ks << 6];
#pragma unroll
        for (int j4 = 0; j4 < 16; ++j4) {
            float4 h4 = hp[j4];
            acc += h4.x * wreg[4 * j4 + 0];
            acc += h4.y * wreg[4 * j4 + 1];
            acc += h4.z * wreg[4 * j4 + 2];
            acc += h4.w * wreg[4 * j4 + 3];
        }

        // combine the two K-halves (lanes l and l+32 share the same r)
        acc += __shfl_xor(acc, 32, 64);

        if (lane < 32) {
            float y = fast_tanh(acc);
            h_lds[cur ^ 1][r] = y;   // next-step state
            outp[s * RES]     = y;   // coalesced 128B per half-wave
        }
        __syncthreads();
    }
}

extern "C" void kernel_launch(void* const* d_in, const int* in_sizes, int n_in,
                              void* d_out, int out_size, void* d_ws, size_t ws_size,
                              hipStream_t stream) {
    const float* x     = (const float*)d_in[0];
    const float* W_in  = (const float*)d_in[1];
    const float* W_res = (const float*)d_in[2];
    float* out = (float*)d_out;
    (void)in_sizes; (void)n_in; (void)out_size; (void)d_ws; (void)ws_size;

    esn_fwd<<<512, 256, 0, stream>>>(x, W_in, W_res, out);
}